// Round 4
// baseline (1354.590 us; speedup 1.0000x reference)
//
#include <hip/hip_runtime.h>
#include <math.h>

#define H 1536
#define E 512
#define T 48
#define S 32
#define V 128
#define NB 256
#define BT 512      // 8 waves
#define JPB 6       // h indices per block
#define ROWS 24     // 4*JPB gate rows per block (per matrix)
#define RPW 3       // rows per wave per matrix
#define CHK 24      // floats per lane chunk (1536/64)
// dynamic LDS: whh2 (64 lanes * 145 float4) + one shared h-gather buffer
#define WHH2_B   (64 * 145 * 16)          // 148480
#define HBUF_B   (64 * 7 * 16)            // 7168
#define DYN_LDS  (WHH2_B + HBUF_B)        // 155648

typedef unsigned long long u64;

// ws layout (4-byte words):
//   [0, 6144)         h2t  : u64[2][H] tagged {f32 value, u32 gen}
//   [8192, 106496)    candp: float[2][S*H] plain f32 candidates
//   [106496, 892928)  xw1g : float[NB][V*ROWS] block-private plain
#define CAND_W  8192
#define XW1_W   106496

__device__ __forceinline__ float sigf(float x) { return 1.0f / (1.0f + expf(-x)); }
__device__ __forceinline__ float wred(float acc) {
#pragma unroll
    for (int off = 32; off; off >>= 1) acc += __shfl_down(acc, off);
    return acc;
}

#define GLD(p)      __hip_atomic_load((p), __ATOMIC_RELAXED, __HIP_MEMORY_SCOPE_AGENT)
#define GST(p, v)   __hip_atomic_store((p), (v), __ATOMIC_RELAXED, __HIP_MEMORY_SCOPE_AGENT)
#define GLD64(p)    __hip_atomic_load((p), __ATOMIC_RELAXED, __HIP_MEMORY_SCOPE_AGENT)
#define GST64(p, v) __hip_atomic_store((p), (v), __ATOMIC_RELAXED, __HIP_MEMORY_SCOPE_AGENT)

__device__ __forceinline__ u64 pkf(float v, unsigned g) {
    return ((u64)g << 32) | (u64)__float_as_uint(v);
}
__device__ __forceinline__ float    pvf(u64 x) { return __uint_as_float((unsigned)x); }
__device__ __forceinline__ unsigned ptg(u64 x) { return (unsigned)(x >> 32); }

// Barrier-free, pred-hop-free dataflow:
//  - h2 fragments are tagged u64 {value, gen}: the h2 gather IS the arrival
//    detection (payload + flag in one coherence hop). No flags, no logit
//    partials, no pred broadcast.
//  - every block redundantly computes the full 32 logits (Wout rows
//    prefetched into registers at round start; drains under the h2 wait)
//    and the argmax. All blocks see bit-identical h2/Wout/bout and use the
//    same op order => identical pred everywhere.
//  - cand stays PLAIN f32: each producer drains its cand stores
//    (__syncthreads => vmcnt(0)) BEFORE its tagged h2 store, and MALL is
//    the point of coherence for agent-scope ops, so h2-tag(gen) observed
//    => that producer's cand(gen) data is visible.
//  - WAR across the 2 parities: entering round k requires observing all
//    256 blocks' h2 tags gen k+1; a producer's gen-(k+1) tag is its LAST
//    act of round k-1, so all its round-(k-1) reads are complete; hence
//    end-of-round-k overwrites of parity (k+1)&1 race nobody.
__global__ __launch_bounds__(BT, 1) void nas_persist(
    const int* __restrict__ input_id, const float* __restrict__ emb,
    const float* __restrict__ Wih1, const float* __restrict__ Whh1,
    const float* __restrict__ bih1, const float* __restrict__ bhh1,
    const float* __restrict__ Wih2, const float* __restrict__ Whh2,
    const float* __restrict__ bih2, const float* __restrict__ bhh2,
    const float* __restrict__ Wout, const float* __restrict__ bout,
    float* __restrict__ out, float* __restrict__ ws)
{
    const int b = blockIdx.x, tid = threadIdx.x;
    const int wave = tid >> 6, lane = tid & 63;

    u64* h2t = (u64*)ws;                    // [parity*H + i]
    float* candp[2] = { ws + CAND_W, ws + CAND_W + S * H };
    float* xw1g = ws + XW1_W + (size_t)b * (V * ROWS);

    extern __shared__ char dyn_lds[];
    float4* whh2s = (float4*)dyn_lds;                 // [lane*145 + row*6 + j]
    float*  hbuf  = (float*)(dyn_lds + WHH2_B);       // chunked, stride 28

    __shared__ float gacc1[ROWS], g2f[ROWS], bsum2[ROWS], zlog[S];
    __shared__ float c1s[JPB], c2s[JPB], c1cand[S * JPB];
    __shared__ int   xid_s, pred_s;

    // ---------------- prologue ----------------
    if (tid < JPB) c2s[tid] = 0.f;
    if (tid < ROWS) {
        int r = (tid / JPB) * H + b * JPB + (tid % JPB);
        bsum2[tid] = bih2[r] + bhh2[r];
    }
    if (tid == 0) xid_s = *input_id;

    // ---- xw1 table -> global ws (uses whh2s region as emb staging) ----
    {
        const int k0 = wave * RPW;
        float4 wiA[RPW], wiB[RPW];
        float  bs[RPW];
#pragma unroll
        for (int i = 0; i < RPW; ++i) {
            int k = k0 + i;
            int r = (k / JPB) * H + b * JPB + (k % JPB);
            const float4* w = (const float4*)(Wih1 + (size_t)r * E);
            wiA[i] = w[lane]; wiB[i] = w[lane + 64];
            bs[i]  = bih1[r] + bhh1[r];
        }
        float4* stage = (float4*)dyn_lds;             // 2048 f4 = 32 KB
        for (int ch = 0; ch < 8; ++ch) {
            const float4* src = (const float4*)(emb + (size_t)ch * 16 * E);
            for (int m = tid; m < 2048; m += BT) stage[m] = src[m];
            __syncthreads();
            for (int vv = 0; vv < 16; ++vv) {
                float4 ea = stage[vv * 128 + lane];
                float4 eb = stage[vv * 128 + 64 + lane];
#pragma unroll
                for (int i = 0; i < RPW; ++i) {
                    float a = wiA[i].x * ea.x + wiA[i].y * ea.y + wiA[i].z * ea.z + wiA[i].w * ea.w
                            + wiB[i].x * eb.x + wiB[i].y * eb.y + wiB[i].z * eb.z + wiB[i].w * eb.w;
                    a = wred(a);
                    if (lane == 0) xw1g[(ch * 16 + vv) * ROWS + (k0 + i)] = a + bs[i];
                }
            }
            __syncthreads();
        }
    }

    // ---- Whh2 -> LDS (lane-chunked, odd-f4 stride 145) ----
    for (int k = 0; k < ROWS; ++k) {
        int r = (k / JPB) * H + b * JPB + (k % JPB);
        const float4* src = (const float4*)(Whh2 + (size_t)r * H);
        if (tid < 384) {
            int l = tid / 6, j = tid % 6;
            whh2s[l * 145 + k * 6 + j] = src[tid];
        }
    }
    __syncthreads();

    // ---- Whh1 + Wih2 rows -> registers ----
    float w1[RPW][CHK], w2[RPW][CHK];
#pragma unroll
    for (int i = 0; i < RPW; ++i) {
        int k = wave * RPW + i;
        int r = (k / JPB) * H + b * JPB + (k % JPB);
        const float4* p1 = (const float4*)(Whh1 + (size_t)r * H) + lane * 6;
        const float4* p2 = (const float4*)(Wih2 + (size_t)r * H) + lane * 6;
#pragma unroll
        for (int j = 0; j < 6; ++j) {
            float4 v1 = p1[j], v2 = p2[j];
            w1[i][4 * j + 0] = v1.x; w1[i][4 * j + 1] = v1.y;
            w1[i][4 * j + 2] = v1.z; w1[i][4 * j + 3] = v1.w;
            w2[i][4 * j + 0] = v2.x; w2[i][4 * j + 1] = v2.y;
            w2[i][4 * j + 2] = v2.z; w2[i][4 * j + 3] = v2.w;
        }
    }
    __syncthreads();

    // ---- h1(0) from xid(0)=input_id; publish cand slot 0 (plain) ----
    if (tid < JPB) {
        const float* xr = xw1g + (size_t)xid_s * ROWS;
        float gi = xr[tid], gg = xr[2 * JPB + tid], go = xr[3 * JPB + tid];
        float cn = sigf(gi) * tanhf(gg);
        c1s[tid] = cn;
        GST(candp[0] + b * JPB + tid, sigf(go) * tanhf(cn));
    }
    __syncthreads();                       // drain cand store (vmcnt 0)
    if (tid < JPB)                         // h2(-1)=0, parity 0, gen 1 (LAST act)
        GST64(h2t + b * JPB + tid, pkf(0.f, 1u));

    // precomputed hbuf scatter maps (stride-28 chunked layout)
    const int m0 = (tid / CHK) * 28 + (tid % CHK);
    const int m1 = ((tid + 512) / CHK) * 28 + ((tid + 512) % CHK);
    const int m2 = ((tid + 1024) / CHK) * 28 + ((tid + 1024) % CHK);

    // ---------------- main loop ----------------
    for (int k = 0; k <= T; ++k) {
        if (k == T && b != 0) return;      // only block 0 runs the tail

        // Wout[k-1] rows -> registers (4 rows/wave; drains under the h2 wait)
        float4 wo[4][6];
        if (k >= 1) {
#pragma unroll
            for (int q = 0; q < 4; ++q) {
                const float4* wp = (const float4*)(Wout
                    + ((size_t)(k - 1) * S + (wave * 4 + q)) * H) + lane * 6;
#pragma unroll
                for (int j = 0; j < 6; ++j) wo[q][j] = wp[j];
            }
        }

        // ---- tagged h2 gather: payload + arrival in one hop ----
        const unsigned expg = (unsigned)(k + 1);
        const u64* h2src = h2t + (size_t)(k & 1) * H;
        u64 a0 = GLD64(h2src + tid);
        u64 a1 = GLD64(h2src + tid + 512);
        u64 a2 = GLD64(h2src + tid + 1024);
        for (;;) {
            if ((ptg(a0) >= expg) && (ptg(a1) >= expg) && (ptg(a2) >= expg)) break;
            __builtin_amdgcn_s_sleep(1);
            a0 = GLD64(h2src + tid);
            a1 = GLD64(h2src + tid + 512);
            a2 = GLD64(h2src + tid + 1024);
        }
        hbuf[m0] = pvf(a0); hbuf[m1] = pvf(a1); hbuf[m2] = pvf(a2);
        __syncthreads();                   // (A) hbuf = h2(k-1)

        float h2c[CHK];
        {
            const float4* hp = (const float4*)hbuf + lane * 7;
#pragma unroll
            for (int j = 0; j < 6; ++j) {
                float4 v = hp[j];
                h2c[4 * j + 0] = v.x; h2c[4 * j + 1] = v.y;
                h2c[4 * j + 2] = v.z; h2c[4 * j + 3] = v.w;
            }
        }

        // local head: logits(k-1), 4 rows per wave (identical in all blocks)
        if (k >= 1) {
#pragma unroll
            for (int q = 0; q < 4; ++q) {
                float acc = 0.f;
#pragma unroll
                for (int j = 0; j < 6; ++j) {
                    float4 v = wo[q][j];
                    acc += v.x * h2c[4 * j + 0] + v.y * h2c[4 * j + 1]
                         + v.z * h2c[4 * j + 2] + v.w * h2c[4 * j + 3];
                }
                acc = wred(acc);
                if (lane == 0)
                    zlog[wave * 4 + q] = acc + bout[(size_t)(k - 1) * S + (wave * 4 + q)];
            }
        }
        __syncthreads();                   // (B) zlog ready; hbuf reads done

        if (k >= 1 && wave == 0) {         // argmax + (b0) out write
            float z = (lane < S) ? zlog[lane] : -1e30f;
            float v = z; int idx = (lane < S) ? lane : 9999;
#pragma unroll
            for (int off = 32; off; off >>= 1) {
                float ov = __shfl_xor(v, off); int oi = __shfl_xor(idx, off);
                if (ov > v || (ov == v && oi < idx)) { v = ov; idx = oi; }
            }
            float e = (lane < S) ? expf(z - v) : 0.f;
#pragma unroll
            for (int off = 32; off; off >>= 1) e += __shfl_xor(e, off);
            if (lane == 0) pred_s = idx;
            if (b == 0 && lane < S) out[(size_t)(k - 1) * S + lane] = z - v - logf(e);
        }
        // gaccH = Whh2 @ h2(k-1): all waves, overlaps wave 0's argmax
        float ahv[RPW];
        if (k < T) {
#pragma unroll
            for (int i = 0; i < RPW; ++i) {
                int kk = wave * RPW + i;
                const float4* wp = whh2s + lane * 145 + kk * 6;
                float ah = 0.f;
#pragma unroll
                for (int j = 0; j < 6; ++j) {
                    float4 v = wp[j];
                    ah += v.x * h2c[4 * j + 0] + v.y * h2c[4 * j + 1]
                        + v.z * h2c[4 * j + 2] + v.w * h2c[4 * j + 3];
                }
                ahv[i] = wred(ah);         // valid at lane 0
            }
        }
        __syncthreads();                   // (C) pred_s visible
        if (k == T) return;                // block 0: out[T-1] written

        const int psel = (k > 0) ? pred_s : 0;
        if (k > 0 && tid < JPB) c1s[tid] = c1cand[psel * JPB + tid];

        // h1(k) plain gather (visibility certified by the h2 tags)
        const float* h1src = candp[k & 1] + (size_t)psel * H;
        float t0 = GLD(h1src + tid);
        float t1 = GLD(h1src + tid + 512);
        float t2 = GLD(h1src + tid + 1024);
        hbuf[m0] = t0; hbuf[m1] = t1; hbuf[m2] = t2;
        __syncthreads();                   // (D) hbuf = h1(k)

        float h1c[CHK];
        {
            const float4* hp = (const float4*)hbuf + lane * 7;
#pragma unroll
            for (int j = 0; j < 6; ++j) {
                float4 v = hp[j];
                h1c[4 * j + 0] = v.x; h1c[4 * j + 1] = v.y;
                h1c[4 * j + 2] = v.z; h1c[4 * j + 3] = v.w;
            }
        }
        // D1: Whh1 @ h1(k), Wih2 @ h1(k) (register weights)
        float a1v[RPW], a2v[RPW];
#pragma unroll
        for (int i = 0; i < RPW; ++i) { a1v[i] = 0.f; a2v[i] = 0.f; }
#pragma unroll
        for (int kk = 0; kk < CHK; ++kk) {
            float h = h1c[kk];
#pragma unroll
            for (int i = 0; i < RPW; ++i) {
                a1v[i] += w1[i][kk] * h;
                a2v[i] += w2[i][kk] * h;
            }
        }
#pragma unroll
        for (int i = 0; i < RPW; ++i) {
            int kk = wave * RPW + i;
            float s1 = wred(a1v[i]);
            float s2 = wred(a2v[i]);
            if (lane == 0) {
                gacc1[kk] = s1;
                g2f[kk]   = s2 + ahv[i] + bsum2[kk];
            }
        }
        __syncthreads();                   // (E) gacc1/g2f ready

        // P2: h2(k) fragment (value kept in reg; tagged store AFTER drain)
        float hn = 0.f;
        if (tid < JPB) {
            float gi = g2f[tid],           gf = g2f[JPB + tid];
            float gg = g2f[2 * JPB + tid], go = g2f[3 * JPB + tid];
            float cn = sigf(gf) * c2s[tid] + sigf(gi) * tanhf(gg);
            c2s[tid] = cn;
            hn = sigf(go) * tanhf(cn);
        }
        // candidates for h1(k+1): all 32 preds; plain publish, parity (k+1)&1
        if (tid < S * JPB) {
            int p = tid / JPB, j = tid % JPB;
            const float* xr = xw1g + (size_t)((k & 3) * S + p) * ROWS;
            float gi = gacc1[j]           + xr[j];
            float gf = gacc1[JPB + j]     + xr[JPB + j];
            float gg = gacc1[2 * JPB + j] + xr[2 * JPB + j];
            float go = gacc1[3 * JPB + j] + xr[3 * JPB + j];
            float cn = sigf(gf) * c1s[j] + sigf(gi) * tanhf(gg);
            c1cand[tid] = cn;
            GST(candp[(k + 1) & 1] + (size_t)p * H + b * JPB + j,
                sigf(go) * tanhf(cn));
        }
        __syncthreads();                   // (F) cand stores drained (vmcnt 0)
        // tagged h2 publish: LAST act of round k => gen k+2 certifies round done
        if (tid < JPB)
            GST64(h2t + (size_t)((k + 1) & 1) * H + b * JPB + tid,
                  pkf(hn, (unsigned)(k + 2)));
    }
}

extern "C" void kernel_launch(void* const* d_in, const int* in_sizes, int n_in,
                              void* d_out, int out_size, void* d_ws, size_t ws_size,
                              hipStream_t stream) {
    const int*   input_id = (const int*)d_in[0];
    const float* emb  = (const float*)d_in[1];
    const float* Wih1 = (const float*)d_in[2];
    const float* Whh1 = (const float*)d_in[3];
    const float* bih1 = (const float*)d_in[4];
    const float* bhh1 = (const float*)d_in[5];
    const float* Wih2 = (const float*)d_in[6];
    const float* Whh2 = (const float*)d_in[7];
    const float* bih2 = (const float*)d_in[8];
    const float* bhh2 = (const float*)d_in[9];
    const float* Wout = (const float*)d_in[10];
    const float* bout = (const float*)d_in[11];
    float* out = (float*)d_out;
    float* ws  = (float*)d_ws;

    // only the tagged h2 region needs zeroing (gen must restart below 1)
    hipMemsetAsync(d_ws, 0, 2 * H * sizeof(u64), stream);

    void* args[] = { (void*)&input_id, (void*)&emb,
                     (void*)&Wih1, (void*)&Whh1, (void*)&bih1, (void*)&bhh1,
                     (void*)&Wih2, (void*)&Whh2, (void*)&bih2, (void*)&bhh2,
                     (void*)&Wout, (void*)&bout, (void*)&out, (void*)&ws };
    hipLaunchCooperativeKernel((void*)nas_persist, dim3(NB), dim3(BT), args,
                               DYN_LDS, stream);
}

// Round 5
// 1207.253 us; speedup vs baseline: 1.1220x; 1.1220x over previous
//
#include <hip/hip_runtime.h>
#include <math.h>

#define H 1536
#define E 512
#define T 48
#define S 32
#define V 128
#define NB 256
#define BT 512      // 8 waves
#define JPB 6       // h indices per block
#define ROWS 24     // 4*JPB gate rows per block (per matrix)
#define RPW 3       // rows per wave per matrix
#define CHK 24      // floats per lane chunk (1536/64)
// dynamic LDS: whh2 (64 lanes * 145 float4) + one shared h-gather buffer
#define WHH2_B   (64 * 145 * 16)          // 148480
#define HBUF_B   (64 * 7 * 16)            // 7168
#define DYN_LDS  (WHH2_B + HBUF_B)        // 155648

// ws layout (4-byte words):
//   [0, 128)            ctr    : 8 arrival counters, 64B stride
//   [4096, 20480)       logitp : float[2][S*NB] plain partials
//   [20480, 23552)      h2g    : float[2][H]
//   [24576, 122880)     candp  : float[2][S*H]
//   [122880, 909312)    xw1g   : float[NB][V*ROWS] block-private
#define LOG_W   4096
#define H2_W    20480
#define CAND_W  24576
#define XW1_W   122880

__device__ __forceinline__ float sigf(float x) { return 1.0f / (1.0f + expf(-x)); }
__device__ __forceinline__ float wred(float acc) {
#pragma unroll
    for (int off = 32; off; off >>= 1) acc += __shfl_down(acc, off);
    return acc;
}

#define GLD(p)    __hip_atomic_load((p), __ATOMIC_RELAXED, __HIP_MEMORY_SCOPE_AGENT)
#define GST(p, v) __hip_atomic_store((p), (v), __ATOMIC_RELAXED, __HIP_MEMORY_SCOPE_AGENT)

// Counter barrier: arrival = ONE atomicAdd per block into one of 8 counters
// (64B apart; 32 blocks each). Detection = 8 lanes polling 8 words.
// Grid-wide poll traffic per sweep: 2K loads vs R1's 65K flag loads --
// the point is to stop poisoning MALL RTT with poll storms.
// Data-before-flag: __syncthreads drains vmcnt before the atomicAdd.
__device__ __forceinline__ void gbar(unsigned* ctr, unsigned& gen) {
    __syncthreads();
    gen++;
    if (threadIdx.x == 0)
        __hip_atomic_fetch_add(&ctr[(blockIdx.x & 7) * 16], 1u,
                               __ATOMIC_RELAXED, __HIP_MEMORY_SCOPE_AGENT);
    if (threadIdx.x < 8) {
        const unsigned tgt = gen * 32u;
        while (GLD(&ctr[threadIdx.x * 16]) < tgt)
            __builtin_amdgcn_s_sleep(1);
    }
    __syncthreads();
}

__global__ __launch_bounds__(BT, 1) void nas_persist(
    const int* __restrict__ input_id, const float* __restrict__ emb,
    const float* __restrict__ Wih1, const float* __restrict__ Whh1,
    const float* __restrict__ bih1, const float* __restrict__ bhh1,
    const float* __restrict__ Wih2, const float* __restrict__ Whh2,
    const float* __restrict__ bih2, const float* __restrict__ bhh2,
    const float* __restrict__ Wout, const float* __restrict__ bout,
    float* __restrict__ out, float* __restrict__ ws)
{
    const int b = blockIdx.x, tid = threadIdx.x;
    const int wave = tid >> 6, lane = tid & 63;

    unsigned* ctr = (unsigned*)ws;
    float* logitp = ws + LOG_W;           // [parity*S*NB + s*NB + b]
    float* h2gp[2]  = { ws + H2_W,   ws + H2_W + H };
    float* candp[2] = { ws + CAND_W, ws + CAND_W + S * H };
    float* xw1g = ws + XW1_W + (size_t)b * (V * ROWS);

    extern __shared__ char dyn_lds[];
    float4* whh2s = (float4*)dyn_lds;                 // [lane*145 + row*6 + j]
    float*  hbuf  = (float*)(dyn_lds + WHH2_B);       // chunked, stride 28

    __shared__ float gacc1[ROWS], g2f[ROWS], bsum2[ROWS], zlog[S], h2f[JPB];
    __shared__ float c1s[JPB], c2s[JPB], c1cand[S * JPB];
    __shared__ int   xid_s, pred_s;

    unsigned gen = 0;

    // ---------------- prologue ----------------
    if (tid < JPB) { c2s[tid] = 0.f; GST(h2gp[0] + b * JPB + tid, 0.f); }
    if (tid < ROWS) {
        int r = (tid / JPB) * H + b * JPB + (tid % JPB);
        bsum2[tid] = bih2[r] + bhh2[r];
    }
    if (tid == 0) xid_s = *input_id;

    // ---- xw1 table -> global ws (uses whh2s region as emb staging) ----
    {
        const int k0 = wave * RPW;
        float4 wiA[RPW], wiB[RPW];
        float  bs[RPW];
#pragma unroll
        for (int i = 0; i < RPW; ++i) {
            int k = k0 + i;
            int r = (k / JPB) * H + b * JPB + (k % JPB);
            const float4* w = (const float4*)(Wih1 + (size_t)r * E);
            wiA[i] = w[lane]; wiB[i] = w[lane + 64];
            bs[i]  = bih1[r] + bhh1[r];
        }
        float4* stage = (float4*)dyn_lds;             // 2048 f4 = 32 KB
        for (int ch = 0; ch < 8; ++ch) {
            const float4* src = (const float4*)(emb + (size_t)ch * 16 * E);
            for (int m = tid; m < 2048; m += BT) stage[m] = src[m];
            __syncthreads();
            for (int vv = 0; vv < 16; ++vv) {
                float4 ea = stage[vv * 128 + lane];
                float4 eb = stage[vv * 128 + 64 + lane];
#pragma unroll
                for (int i = 0; i < RPW; ++i) {
                    float a = wiA[i].x * ea.x + wiA[i].y * ea.y + wiA[i].z * ea.z + wiA[i].w * ea.w
                            + wiB[i].x * eb.x + wiB[i].y * eb.y + wiB[i].z * eb.z + wiB[i].w * eb.w;
                    a = wred(a);
                    if (lane == 0) xw1g[(ch * 16 + vv) * ROWS + (k0 + i)] = a + bs[i];
                }
            }
            __syncthreads();
        }
    }

    // ---- Whh2 -> LDS (lane-chunked, odd-f4 stride 145) ----
    for (int k = 0; k < ROWS; ++k) {
        int r = (k / JPB) * H + b * JPB + (k % JPB);
        const float4* src = (const float4*)(Whh2 + (size_t)r * H);
        if (tid < 384) {
            int l = tid / 6, j = tid % 6;
            whh2s[l * 145 + k * 6 + j] = src[tid];
        }
    }
    __syncthreads();

    // ---- Whh1 + Wih2 rows -> registers ----
    float w1[RPW][CHK], w2[RPW][CHK];
#pragma unroll
    for (int i = 0; i < RPW; ++i) {
        int k = wave * RPW + i;
        int r = (k / JPB) * H + b * JPB + (k % JPB);
        const float4* p1 = (const float4*)(Whh1 + (size_t)r * H) + lane * 6;
        const float4* p2 = (const float4*)(Wih2 + (size_t)r * H) + lane * 6;
#pragma unroll
        for (int j = 0; j < 6; ++j) {
            float4 v1 = p1[j], v2 = p2[j];
            w1[i][4 * j + 0] = v1.x; w1[i][4 * j + 1] = v1.y;
            w1[i][4 * j + 2] = v1.z; w1[i][4 * j + 3] = v1.w;
            w2[i][4 * j + 0] = v2.x; w2[i][4 * j + 1] = v2.y;
            w2[i][4 * j + 2] = v2.z; w2[i][4 * j + 3] = v2.w;
        }
    }
    __syncthreads();

    // ---- h1(0) from xid(0)=input_id; publish candidate slot 0, parity 0 ----
    if (tid < JPB) {
        const float* xr = xw1g + (size_t)xid_s * ROWS;
        float gi = xr[tid], gg = xr[2 * JPB + tid], go = xr[3 * JPB + tid];
        float cn = sigf(gi) * tanhf(gg);
        c1s[tid] = cn;
        GST(candp[0] + b * JPB + tid, sigf(go) * tanhf(cn));   // slot 0, parity 0
    }
    gbar(ctr, gen);                        // gen 1: prologue publishes certified

    // precomputed hbuf scatter maps (stride-28 chunked layout)
    const int m0 = (tid / CHK) * 28 + (tid % CHK);
    const int m1 = ((tid + 512) / CHK) * 28 + ((tid + 512) % CHK);
    const int m2 = ((tid + 1024) / CHK) * 28 + ((tid + 1024) % CHK);

    // ---------------- main loop: ONE counter-barrier per round ----------------
    for (int k = 0; k <= T; ++k) {
        // 1) pred-critical logit-partial loads: FIRST in the vmcnt FIFO
        float pv[16];
        const float* lp = logitp + (size_t)(k & 1) * (S * NB)
                          + (tid >> 4) * NB + (tid & 15) * 16;
        if (k > 0) {
#pragma unroll
            for (int i = 0; i < 16; ++i) pv[i] = GLD(lp + i);
        }
        // 2) h2(k-1) gather (feeds gaccH + next partials; off the pred path)
        const float* h2src = h2gp[k & 1];
        float u0 = GLD(h2src + tid);
        float u1 = GLD(h2src + tid + 512);
        float u2 = GLD(h2src + tid + 1024);
        // 3) cold Wout slice LAST (drain point is the tail publish)
        float wcol[JPB];
        if (k < T && wave == 0 && lane < S) {
            const float* wp = Wout + ((size_t)k * S + lane) * H + b * JPB;
#pragma unroll
            for (int j = 0; j < JPB; ++j) wcol[j] = wp[j];
        }

        // logits(k-1): fixed-order reduce (bitwise identical in every block)
        if (k > 0) {
            float acc = 0.f;
#pragma unroll
            for (int i = 0; i < 16; ++i) acc += pv[i];
#pragma unroll
            for (int off = 8; off; off >>= 1) acc += __shfl_down(acc, off, 16);
            if ((tid & 15) == 0)
                zlog[tid >> 4] = acc + bout[(size_t)(k - 1) * S + (tid >> 4)];
        }
        __syncthreads();
        if (k > 0) {
            if (wave == 0) {
                float z = (lane < S) ? zlog[lane] : -1e30f;
                float v = z; int idx = (lane < S) ? lane : 9999;
#pragma unroll
                for (int off = 32; off; off >>= 1) {
                    float ov = __shfl_xor(v, off); int oi = __shfl_xor(idx, off);
                    if (ov > v || (ov == v && oi < idx)) { v = ov; idx = oi; }
                }
                float e = (lane < S) ? expf(z - v) : 0.f;
#pragma unroll
                for (int off = 32; off; off >>= 1) e += __shfl_xor(e, off);
                if (lane == 0) pred_s = idx;
                if (b == 0 && lane < S) out[(size_t)(k - 1) * S + lane] = z - v - logf(e);
            }
            __syncthreads();
        }
        if (k == T) return;                // out[T-1] written; done
        const int psel = (k > 0) ? pred_s : 0;
        if (k > 0 && tid < JPB) c1s[tid] = c1cand[psel * JPB + tid];

        // issue h1 gather NOW; h2 LDS hop + gaccH hide its latency
        const float* h1src = candp[k & 1] + (size_t)psel * H;
        float t0 = GLD(h1src + tid);
        float t1 = GLD(h1src + tid + 512);
        float t2 = GLD(h1src + tid + 1024);

        hbuf[m0] = u0; hbuf[m1] = u1; hbuf[m2] = u2;   // h2 -> LDS
        __syncthreads();
        float h2c[CHK];
        {
            const float4* hp = (const float4*)hbuf + lane * 7;
#pragma unroll
            for (int j = 0; j < 6; ++j) {
                float4 v = hp[j];
                h2c[4 * j + 0] = v.x; h2c[4 * j + 1] = v.y;
                h2c[4 * j + 2] = v.z; h2c[4 * j + 3] = v.w;
            }
        }
        // Whh2 @ h2(k-1) dots (registers; h1 gather in flight underneath)
        float ahv[RPW];
#pragma unroll
        for (int i = 0; i < RPW; ++i) {
            int kk = wave * RPW + i;
            const float4* wp = whh2s + lane * 145 + kk * 6;
            float ah = 0.f;
#pragma unroll
            for (int j = 0; j < 6; ++j) {
                float4 v = wp[j];
                ah += v.x * h2c[4 * j + 0] + v.y * h2c[4 * j + 1]
                    + v.z * h2c[4 * j + 2] + v.w * h2c[4 * j + 3];
            }
            ahv[i] = wred(ah);             // valid at lane 0
        }
        __syncthreads();                   // hbuf free for h1
        hbuf[m0] = t0; hbuf[m1] = t1; hbuf[m2] = t2;
        __syncthreads();
        float h1c[CHK];
        {
            const float4* hp = (const float4*)hbuf + lane * 7;
#pragma unroll
            for (int j = 0; j < 6; ++j) {
                float4 v = hp[j];
                h1c[4 * j + 0] = v.x; h1c[4 * j + 1] = v.y;
                h1c[4 * j + 2] = v.z; h1c[4 * j + 3] = v.w;
            }
        }
        // D1: Whh1 @ h1(k), Wih2 @ h1(k) (register weights)
        float a1[RPW], a2[RPW];
#pragma unroll
        for (int i = 0; i < RPW; ++i) { a1[i] = 0.f; a2[i] = 0.f; }
#pragma unroll
        for (int kk = 0; kk < CHK; ++kk) {
            float h = h1c[kk];
#pragma unroll
            for (int i = 0; i < RPW; ++i) {
                a1[i] += w1[i][kk] * h;
                a2[i] += w2[i][kk] * h;
            }
        }
#pragma unroll
        for (int i = 0; i < RPW; ++i) {
            int kk = wave * RPW + i;
            float s1 = wred(a1[i]);
            float s2 = wred(a2[i]);
            if (lane == 0) {
                gacc1[kk] = s1;
                g2f[kk]   = s2 + ahv[i] + bsum2[kk];
            }
        }
        __syncthreads();

        // P2: h2(k) fragment -> publish to parity (k+1)&1
        if (tid < JPB) {
            float gi = g2f[tid],           gf = g2f[JPB + tid];
            float gg = g2f[2 * JPB + tid], go = g2f[3 * JPB + tid];
            float cn = sigf(gf) * c2s[tid] + sigf(gi) * tanhf(gg);
            c2s[tid] = cn;
            float hn = sigf(go) * tanhf(cn);
            h2f[tid] = hn;
            GST(h2gp[(k + 1) & 1] + b * JPB + tid, hn);
        }
        // candidates for h1(k+1): all 32 possible preds; publish fragments
        if (tid < S * JPB) {
            int p = tid / JPB, j = tid % JPB;
            const float* xr = xw1g + (size_t)((k & 3) * S + p) * ROWS;
            float gi = gacc1[j]           + xr[j];
            float gf = gacc1[JPB + j]     + xr[JPB + j];
            float gg = gacc1[2 * JPB + j] + xr[2 * JPB + j];
            float go = gacc1[3 * JPB + j] + xr[3 * JPB + j];
            float cn = sigf(gf) * c1s[j] + sigf(gi) * tanhf(gg);
            c1cand[tid] = cn;
            GST(candp[(k + 1) & 1] + (size_t)p * H + b * JPB + j,
                sigf(go) * tanhf(cn));
        }
        __syncthreads();                   // h2f visible to wave 0
        // producer-side partial logits(k): this block's 6-column contribution
        if (wave == 0 && lane < S) {
            float p = 0.f;
#pragma unroll
            for (int j = 0; j < JPB; ++j) p += wcol[j] * h2f[j];
            GST(logitp + (size_t)((k + 1) & 1) * (S * NB) + lane * NB + b, p);
        }
        gbar(ctr, gen);                    // gen k+2: round-k publishes certified
    }
}

extern "C" void kernel_launch(void* const* d_in, const int* in_sizes, int n_in,
                              void* d_out, int out_size, void* d_ws, size_t ws_size,
                              hipStream_t stream) {
    const int*   input_id = (const int*)d_in[0];
    const float* emb  = (const float*)d_in[1];
    const float* Wih1 = (const float*)d_in[2];
    const float* Whh1 = (const float*)d_in[3];
    const float* bih1 = (const float*)d_in[4];
    const float* bhh1 = (const float*)d_in[5];
    const float* Wih2 = (const float*)d_in[6];
    const float* Whh2 = (const float*)d_in[7];
    const float* bih2 = (const float*)d_in[8];
    const float* bhh2 = (const float*)d_in[9];
    const float* Wout = (const float*)d_in[10];
    const float* bout = (const float*)d_in[11];
    float* out = (float*)d_out;
    float* ws  = (float*)d_ws;

    // only the 8 arrival counters need zeroing (monotonic, no reset)
    hipMemsetAsync(d_ws, 0, 512, stream);

    void* args[] = { (void*)&input_id, (void*)&emb,
                     (void*)&Wih1, (void*)&Whh1, (void*)&bih1, (void*)&bhh1,
                     (void*)&Wih2, (void*)&Whh2, (void*)&bih2, (void*)&bhh2,
                     (void*)&Wout, (void*)&bout, (void*)&out, (void*)&ws };
    hipLaunchCooperativeKernel((void*)nas_persist, dim3(NB), dim3(BT), args,
                               DYN_LDS, stream);
}